// Round 1
// baseline (436.317 us; speedup 1.0000x reference)
//
#include <hip/hip_runtime.h>
#include <hip/hip_bf16.h>
#include <math.h>

// Problem dims (fixed by reference)
#define BB 16
#define SS 2048
#define HH 512
#define AA 256
#define NCH 64          // chunks along t for the a-scan
#define CT  (SS/NCH)    // 32 tokens per chunk
#define XST 72          // LDS row stride in bf16 (64 + 8 pad; 144B = 4 banks mod 32 -> 2-way free)

typedef short bf16x8 __attribute__((ext_vector_type(8)));
typedef float f32x4  __attribute__((ext_vector_type(4)));

__device__ __forceinline__ short f2bf(float f) {
    union { __hip_bfloat16 h; short s; } u;
    u.h = __float2bfloat16(f);
    return u.s;
}

__device__ __forceinline__ void nt_store4(float4 v, float4* p) {
    f32x4 o = {v.x, v.y, v.z, v.w};
    __builtin_nontemporal_store(o, (f32x4*)p);
}

// ---------------------------------------------------------------------------
// Kernel 0: W (fp32, [A,H]) -> bf16 once. 131072 elems, float4 per thread.
// ---------------------------------------------------------------------------
__global__ __launch_bounds__(256) void convW_kernel(
    const float* __restrict__ W, short* __restrict__ Wb)
{
    int i = blockIdx.x * 256 + threadIdx.x;      // float4 index, 32768 total
    float4 v = ((const float4*)W)[i];
    short4 o = make_short4(f2bf(v.x), f2bf(v.y), f2bf(v.z), f2bf(v.w));
    ((short4*)Wb)[i] = o;
}

// ---------------------------------------------------------------------------
// Kernel 1: e[tok] = sum_a q[a] * tanh( sum_h W[a,h]*x[tok,h] )  via bf16 MFMA.
// Block: 256 thr (4 waves, 2x2 wave grid), tile 64 tok x 256 a, BK=64.
// (unchanged from previous round — measured-good)
// ---------------------------------------------------------------------------
__global__ __launch_bounds__(256, 2) void gemm_e_mfma(
    const float* __restrict__ x, const short* __restrict__ Wb,
    const float* __restrict__ q, float* __restrict__ e)
{
    __shared__ short Xl[64 * XST];    //  9216 B
    __shared__ short Wl[256 * XST];   // 36864 B
    __shared__ float epart[2][64];

    const int tid  = threadIdx.x;
    const int lane = tid & 63;
    const int wv   = tid >> 6;
    const int wm   = wv & 1;          // token half (32 each)
    const int wn   = wv >> 1;         // a half (128 each)
    const int quad = lane >> 4;
    const int col  = lane & 15;
    const long tok0 = (long)blockIdx.x * 64;

    f32x4 acc[2][8];
    #pragma unroll
    for (int mt = 0; mt < 2; mt++)
        #pragma unroll
        for (int nt = 0; nt < 8; nt++) acc[mt][nt] = (f32x4){0.f, 0.f, 0.f, 0.f};

    for (int kc = 0; kc < HH; kc += 64) {
        __syncthreads();
        // Stage X: 64 tok x 64 k fp32 -> bf16. 512 segs of 8 floats, 2/thread.
        #pragma unroll
        for (int i = 0; i < 2; i++) {
            int task = i * 256 + tid;
            int row = task >> 3, seg = task & 7;
            const float* src = &x[(tok0 + row) * HH + kc + seg * 8];
            float4 v0 = *(const float4*)src;
            float4 v1 = *(const float4*)(src + 4);
            bf16x8 o;
            o[0] = f2bf(v0.x); o[1] = f2bf(v0.y); o[2] = f2bf(v0.z); o[3] = f2bf(v0.w);
            o[4] = f2bf(v1.x); o[5] = f2bf(v1.y); o[6] = f2bf(v1.z); o[7] = f2bf(v1.w);
            *(bf16x8*)&Xl[row * XST + seg * 8] = o;
        }
        // Stage W: 256 a x 64 k bf16 direct. 2048 segs of 8 bf16, 8/thread.
        #pragma unroll
        for (int i = 0; i < 8; i++) {
            int task = i * 256 + tid;
            int row = task >> 3, seg = task & 7;
            bf16x8 v = *(const bf16x8*)&Wb[row * HH + kc + seg * 8];
            *(bf16x8*)&Wl[row * XST + seg * 8] = v;
        }
        __syncthreads();
        #pragma unroll
        for (int kk = 0; kk < 64; kk += 32) {
            bf16x8 af[2], bfr[8];
            #pragma unroll
            for (int mt = 0; mt < 2; mt++)
                af[mt] = *(bf16x8*)&Xl[(wm * 32 + mt * 16 + col) * XST + kk + quad * 8];
            #pragma unroll
            for (int nt = 0; nt < 8; nt++)
                bfr[nt] = *(bf16x8*)&Wl[(wn * 128 + nt * 16 + col) * XST + kk + quad * 8];
            #pragma unroll
            for (int mt = 0; mt < 2; mt++)
                #pragma unroll
                for (int nt = 0; nt < 8; nt++)
                    acc[mt][nt] = __builtin_amdgcn_mfma_f32_16x16x32_bf16(
                        af[mt], bfr[nt], acc[mt][nt], 0, 0, 0);
        }
    }

    // Epilogue: e = q . tanh(act). Lane holds act[token=...quad*4+reg][a=...col].
    float qv[8];
    #pragma unroll
    for (int nt = 0; nt < 8; nt++) qv[nt] = q[wn * 128 + nt * 16 + col];
    #pragma unroll
    for (int mt = 0; mt < 2; mt++) {
        #pragma unroll
        for (int reg = 0; reg < 4; reg++) {
            float sv = 0.f;
            #pragma unroll
            for (int nt = 0; nt < 8; nt++) sv += qv[nt] * tanhf(acc[mt][nt][reg]);
            // reduce over the 16 cols (lanes within quad)
            #pragma unroll
            for (int off = 1; off < 16; off <<= 1) sv += __shfl_xor(sv, off, 64);
            if (col == 0)
                epart[wn][wm * 32 + mt * 16 + quad * 4 + reg] = sv;
        }
    }
    __syncthreads();
    if (tid < 64) e[tok0 + tid] = epart[0][tid] + epart[1][tid];
}

// ---------------------------------------------------------------------------
// Kernel 2: per batch b: m = max_t e; w = exp(e-m); Z = inclusive prefix; 1/Z.
// v2: shuffle-based max reduce + wave-level inclusive scan (2 barriers total,
// vs 16 barrier'd Hillis-Steele steps before). Same summation order per thread
// (sequential 8) then ascending lane/wave order -> numerically equivalent.
// ---------------------------------------------------------------------------
__global__ __launch_bounds__(256) void softmax_scan_kernel(
    const float* __restrict__ e, float* __restrict__ w, float* __restrict__ zinv)
{
    __shared__ float wmax[4];
    __shared__ float wsum[4];
    const int b = blockIdx.x, tid = threadIdx.x;
    const int lane = tid & 63, wvi = tid >> 6;
    const float* eb = e + b * SS;
    float v[8];
    #pragma unroll
    for (int j = 0; j < 8; j++) v[j] = eb[tid * 8 + j];
    float m = v[0];
    #pragma unroll
    for (int j = 1; j < 8; j++) m = fmaxf(m, v[j]);
    #pragma unroll
    for (int off = 32; off > 0; off >>= 1) m = fmaxf(m, __shfl_xor(m, off, 64));
    if (lane == 0) wmax[wvi] = m;
    __syncthreads();
    const float mb = fmaxf(fmaxf(wmax[0], wmax[1]), fmaxf(wmax[2], wmax[3]));
    float we[8], pf[8], p = 0.f;
    #pragma unroll
    for (int j = 0; j < 8; j++) { we[j] = expf(v[j] - mb); p += we[j]; pf[j] = p; }
    // inclusive scan of p across the wave
    float incl = p;
    #pragma unroll
    for (int off = 1; off < 64; off <<= 1) {
        float t = __shfl_up(incl, off, 64);
        if (lane >= off) incl += t;
    }
    if (lane == 63) wsum[wvi] = incl;
    __syncthreads();
    float base = 0.f;
    for (int ww = 0; ww < wvi; ww++) base += wsum[ww];
    const float excl = base + incl - p;
    #pragma unroll
    for (int j = 0; j < 8; j++) {
        float Z = excl + pf[j];
        w[b * SS + tid * 8 + j]    = we[j];
        zinv[b * SS + tid * 8 + j] = 1.0f / Z;
    }
}

// ---------------------------------------------------------------------------
// Kernel 3: d[b,s,t] = (t<=s) ? w[b,t]*zinv[b,s] : 0.
// v2: 16 s-rows per block (same b): load w row slice ONCE into registers,
// reuse across 16 rows -> 32 NT stores/thread, 16x fewer blocks, 16x less
// L2 w-reread, much more store-level parallelism per thread. Write-bound.
// ---------------------------------------------------------------------------
__global__ __launch_bounds__(256) void write_d_kernel(
    const float* __restrict__ w, const float* __restrict__ zinv,
    float* __restrict__ dout)
{
    const int blk = blockIdx.x;            // BB * SS/16 = 2048
    const int b  = blk >> 7;
    const int sg = blk & 127;
    const int s0 = sg << 4;
    const int tid = threadIdx.x;
    const float4* wb = (const float4*)(w + b * SS);
    const float4 wa = wb[tid];             // cols 4*tid .. 4*tid+3
    const float4 wc = wb[tid + 256];       // cols 4*(tid+256) ..
    const int ta = tid * 4;
    const int tc = (tid + 256) * 4;
    const float* zb = zinv + b * SS + s0;
    float4* rowbase = (float4*)(dout + (size_t)(b * SS + s0) * SS);
    #pragma unroll
    for (int r = 0; r < 16; r++) {
        const int s = s0 + r;
        const float zi = zb[r];
        float4 oa, oc;
        oa.x = (ta + 0 <= s) ? wa.x * zi : 0.f;
        oa.y = (ta + 1 <= s) ? wa.y * zi : 0.f;
        oa.z = (ta + 2 <= s) ? wa.z * zi : 0.f;
        oa.w = (ta + 3 <= s) ? wa.w * zi : 0.f;
        oc.x = (tc + 0 <= s) ? wc.x * zi : 0.f;
        oc.y = (tc + 1 <= s) ? wc.y * zi : 0.f;
        oc.z = (tc + 2 <= s) ? wc.z * zi : 0.f;
        oc.w = (tc + 3 <= s) ? wc.w * zi : 0.f;
        nt_store4(oa, rowbase + (size_t)r * (SS / 4) + tid);
        nt_store4(oc, rowbase + (size_t)r * (SS / 4) + tid + 256);
    }
}

// ---------------------------------------------------------------------------
// Kernel 4a: P[b,c,h] = sum_{t in chunk c} w[b,t]*x[b,t,h]   (chunk sums)
// ---------------------------------------------------------------------------
__global__ __launch_bounds__(128) void scan_part_kernel(
    const float* __restrict__ x, const float* __restrict__ w, float* __restrict__ P)
{
    const int blk = blockIdx.x;
    const int b = blk >> 6;        // NCH = 64
    const int c = blk & (NCH - 1);
    const int tid = threadIdx.x;   // h-float4 lane, 0..127
    const int t0 = c * CT;
    const float4* xb = (const float4*)(x + ((size_t)b * SS + t0) * HH);
    const float* wb = w + b * SS + t0;
    float4 acc = make_float4(0.f, 0.f, 0.f, 0.f);
    #pragma unroll 4
    for (int t = 0; t < CT; t++) {
        float wt = wb[t];
        float4 xv = xb[(size_t)t * (HH / 4) + tid];
        acc.x = fmaf(wt, xv.x, acc.x);
        acc.y = fmaf(wt, xv.y, acc.y);
        acc.z = fmaf(wt, xv.z, acc.z);
        acc.w = fmaf(wt, xv.w, acc.w);
    }
    ((float4*)P)[(size_t)blk * (HH / 4) + tid] = acc;
}

// ---------------------------------------------------------------------------
// Kernel 4b (fused prefix+emit): base = sum_{c'<c} P[b,c'] read directly from
// L2-resident P (removes the serial 16-block chunk_prefix kernel + a launch;
// same ascending-c summation order -> bit-identical base). Then
// a[b,t,h] = (base + running prefix within chunk) * zinv[b,t].
// ---------------------------------------------------------------------------
__global__ __launch_bounds__(128) void scan_emit_kernel(
    const float* __restrict__ x, const float* __restrict__ w,
    const float* __restrict__ zinv, const float* __restrict__ P,
    float* __restrict__ aout)
{
    const int blk = blockIdx.x;
    const int b = blk >> 6;        // NCH = 64
    const int c = blk & (NCH - 1);
    const int tid = threadIdx.x;
    const float4* Pb = (const float4*)P + (size_t)b * NCH * (HH / 4) + tid;
    float4 base = make_float4(0.f, 0.f, 0.f, 0.f);
    for (int cc = 0; cc < c; cc++) {
        float4 p = Pb[(size_t)cc * (HH / 4)];
        base.x += p.x; base.y += p.y; base.z += p.z; base.w += p.w;
    }
    const int t0 = c * CT;
    const float4* xb = (const float4*)(x + ((size_t)b * SS + t0) * HH);
    const float* wb = w + b * SS + t0;
    const float* zb = zinv + b * SS + t0;
    float4* ab = (float4*)(aout + ((size_t)b * SS + t0) * HH);
    #pragma unroll 4
    for (int t = 0; t < CT; t++) {
        float wt = wb[t];
        float zi = zb[t];
        float4 xv = xb[(size_t)t * (HH / 4) + tid];
        base.x = fmaf(wt, xv.x, base.x);
        base.y = fmaf(wt, xv.y, base.y);
        base.z = fmaf(wt, xv.z, base.z);
        base.w = fmaf(wt, xv.w, base.w);
        float4 o = make_float4(base.x * zi, base.y * zi, base.z * zi, base.w * zi);
        nt_store4(o, &ab[(size_t)t * (HH / 4) + tid]);
    }
}

extern "C" void kernel_launch(void* const* d_in, const int* in_sizes, int n_in,
                              void* d_out, int out_size, void* d_ws, size_t ws_size,
                              hipStream_t stream)
{
    const float* x = (const float*)d_in[0];   // [B,S,H]
    const float* W = (const float*)d_in[1];   // [A,H]
    const float* q = (const float*)d_in[2];   // [1,A]
    float* out  = (float*)d_out;
    float* aout = out;                         // [B,S,1,H]
    float* dout = out + (size_t)BB * SS * HH;  // [B,S,1,S]

    float* ws   = (float*)d_ws;
    float* e    = ws;                           // B*S
    float* w    = ws + BB * SS;                 // B*S
    float* zinv = ws + 2 * BB * SS;             // B*S
    float* P    = ws + 3 * BB * SS;             // B*NCH*H = 2 MB
    short* Wb   = (short*)(ws + 3 * BB * SS + BB * NCH * HH);  // A*H bf16

    hipLaunchKernelGGL(convW_kernel, dim3(AA * HH / 4 / 256), dim3(256), 0, stream,
                       W, Wb);
    hipLaunchKernelGGL(gemm_e_mfma, dim3(BB * SS / 64), dim3(256), 0, stream,
                       x, Wb, q, e);
    hipLaunchKernelGGL(softmax_scan_kernel, dim3(BB), dim3(256), 0, stream,
                       e, w, zinv);
    hipLaunchKernelGGL(write_d_kernel, dim3(BB * SS / 16), dim3(256), 0, stream,
                       w, zinv, dout);
    hipLaunchKernelGGL(scan_part_kernel, dim3(BB * NCH), dim3(128), 0, stream,
                       x, w, P);
    hipLaunchKernelGGL(scan_emit_kernel, dim3(BB * NCH), dim3(128), 0, stream,
                       x, w, zinv, P, aout);
}